// Round 17
// baseline (561.541 us; speedup 1.0000x reference)
//
#include <hip/hip_runtime.h>
#include <hip/hip_bf16.h>
#include <math.h>

// ---------------------------------------------------------------------------
// FlaxLTX2AudioAttnBlock: GN -> QKV proj -> softmax(QK^T/sqrt(C)) V -> proj -> +x
// B=4, N=4096 tokens/batch, C=512, G=32 groups.
// R17: (1) __align__(16) on fp8 LDS tiles -> guaranteed ds_read_b128 (char
//      arrays were align-1; split reads caused the residual 5.24e6 bank
//      conflicts); (2) scores/pv launch_bounds (512,4)->(512,6) -> 3 blocks/CU.
//      Arithmetic unchanged -> output bit-identical to R16 (absmax 0.03125).
// ---------------------------------------------------------------------------

typedef __bf16 bf16;
typedef float f32x4 __attribute__((ext_vector_type(4)));
typedef __bf16 bf16x8 __attribute__((ext_vector_type(8)));
typedef __bf16 bf16x4 __attribute__((ext_vector_type(4)));
typedef long long i64;
typedef __attribute__((ext_vector_type(2))) long long i64x2;

#define AS1 __attribute__((address_space(1)))
#define AS3 __attribute__((address_space(3)))

#define NB   4
#define NTOK 4096
#define CCH  512
#define NGRP 32

__device__ __forceinline__ void gload_lds16(const void* g, void* l) {
  __builtin_amdgcn_global_load_lds((AS1 void*)(g), (AS3 void*)(l), 16, 0, 0);
}

// f32 -> OCP e4m3 (RNE, saturating). HW cvt if available, manual otherwise.
__device__ __forceinline__ unsigned char to_e4m3(float f) {
#if __has_builtin(__builtin_amdgcn_cvt_pk_fp8_f32)
  return (unsigned char)(__builtin_amdgcn_cvt_pk_fp8_f32(f, 0.f, 0, false) & 0xff);
#else
  const unsigned u = __float_as_uint(f);
  const unsigned s = (u >> 24) & 0x80;
  const float a = fabsf(f);
  if (a >= 448.f) return (unsigned char)(s | 0x7E);
  if (a < 0.015625f) {
    const int m = (int)rintf(a * 512.f);
    return (unsigned char)(s | m);
  }
  int e = (int)((u >> 23) & 0xff) - 127;
  const float q = exp2f((float)(e - 3));
  int r = (int)rintf(a / q);
  if (r == 16) { e += 1; r = 8; }
  return (unsigned char)(s | ((e + 7) << 3) | (r - 8));
#endif
}

// k-byte permutation within each 128B block: granule g -> (g&3)*4 + (g>>2).
__device__ __forceinline__ int kperm(int col) {
  const int g = (col >> 3) & 15;
  const int gp = (g & 3) * 4 + (g >> 2);
  return (col & ~127) | (gp * 8) | (col & 7);
}

// ---------------- GroupNorm stage 1: partial sums ---------------------------
__global__ __launch_bounds__(256) void gn_partial(const float4* __restrict__ x4,
                                                  float* __restrict__ partials) {
  const int chunk = blockIdx.x, b = blockIdx.y;
  const int tid = threadIdx.x;
  const size_t base = ((size_t)b * NTOK + (size_t)chunk * 64) * 128;  // float4s
  float s = 0.f, ss = 0.f;
  #pragma unroll 4
  for (int it = 0; it < 32; ++it) {
    const float4 v = x4[base + it * 256 + tid];
    s  += v.x + v.y + v.z + v.w;
    ss += v.x * v.x + v.y * v.y + v.z * v.z + v.w * v.w;
  }
  __shared__ float ls[256], lss[256];
  ls[tid] = s; lss[tid] = ss;
  __syncthreads();
  if (tid < 32) {
    float ps = 0.f, pss = 0.f;
    #pragma unroll
    for (int j = 0; j < 4; ++j) {
      ps  += ls[tid * 4 + j] + ls[128 + tid * 4 + j];
      pss += lss[tid * 4 + j] + lss[128 + tid * 4 + j];
    }
    const size_t o = (((size_t)b * 64 + chunk) * 32 + tid) * 2;
    partials[o] = ps; partials[o + 1] = pss;
  }
}

// ---------------- GroupNorm stage 2: reduce 64 chunks -> stats --------------
__global__ __launch_bounds__(128) void gn_reduce(const float* __restrict__ partials,
                                                 float* __restrict__ stats) {
  const int tid = threadIdx.x;          // tid = b*32 + g
  const int b = tid >> 5, g = tid & 31;
  float s = 0.f, ss = 0.f;
  for (int c = 0; c < 64; ++c) {
    const size_t o = (((size_t)b * 64 + c) * 32 + g) * 2;
    s += partials[o]; ss += partials[o + 1];
  }
  const float inv = 1.f / (NTOK * 16.f);
  const float mean = s * inv;
  const float var = ss * inv - mean * mean;
  stats[tid * 2] = mean;
  stats[tid * 2 + 1] = rsqrtf(var + 1e-6f);
}

// ---------------- normalize + affine + cast to bf16 -------------------------
__global__ __launch_bounds__(256) void gn_apply(const float4* __restrict__ x4,
                                                const float* __restrict__ stats,
                                                const float* __restrict__ gsc,
                                                const float* __restrict__ gbi,
                                                bf16* __restrict__ hf) {
  const int i = blockIdx.x * 256 + threadIdx.x;   // over 2,097,152 float4s
  const float4 v = x4[i];
  const size_t e = (size_t)i * 4;
  const int c = (int)(e & (CCH - 1));
  const int b = (int)(e >> 21);
  const int g = c >> 4;
  const float mean = stats[(b * NGRP + g) * 2];
  const float rstd = stats[(b * NGRP + g) * 2 + 1];
  bf16x4 o;
  o[0] = (bf16)((v.x - mean) * rstd * gsc[c + 0] + gbi[c + 0]);
  o[1] = (bf16)((v.y - mean) * rstd * gsc[c + 1] + gbi[c + 1]);
  o[2] = (bf16)((v.z - mean) * rstd * gsc[c + 2] + gbi[c + 2]);
  o[3] = (bf16)((v.w - mean) * rstd * gsc[c + 3] + gbi[c + 3]);
  *reinterpret_cast<bf16x4*>(&hf[e]) = o;
}

// ---------------- weight transpose+cast (wq, wk) + bias concat --------------
__global__ __launch_bounds__(256) void wcast_t(const float* __restrict__ wq,
                                               const float* __restrict__ wk,
                                               const float* __restrict__ bq,
                                               const float* __restrict__ bk,
                                               bf16* __restrict__ dst,
                                               float* __restrict__ bcat) {
  const int w = blockIdx.y;                // 0 = wq, 1 = wk
  const float* src = (w == 0) ? wq : wk;
  bf16* out = dst + (size_t)w * CCH * CCH;
  const int t = blockIdx.x;                // 8x8 tiles of 64x64
  const int tr = t >> 3, tc = t & 7;
  if (t == 0) {
    const float* bsrc = (w == 0) ? bq : bk;
    for (int i = threadIdx.x; i < CCH; i += 256) bcat[w * CCH + i] = bsrc[i];
  }
  __shared__ float tile[64][65];
  for (int i = threadIdx.x; i < 4096; i += 256) {
    const int r = i >> 6, c = i & 63;
    tile[r][c] = src[(size_t)(tr * 64 + r) * CCH + tc * 64 + c];
  }
  __syncthreads();
  for (int i = threadIdx.x; i < 4096; i += 256) {
    const int r = i >> 6, c = i & 63;
    out[(size_t)(tc * 64 + r) * CCH + tr * 64 + c] = (bf16)tile[c][r];
  }
}

// ---------------- prep: W'^T = (wv@wo)^T bf16; block 0 also bpv -------------
__global__ __launch_bounds__(256) void prep_w(const float* __restrict__ wv,
                                              const float* __restrict__ wo,
                                              const float* __restrict__ bv,
                                              const float* __restrict__ bo,
                                              bf16* __restrict__ wpT,
                                              float* __restrict__ bpv) {
  const int ta = blockIdx.x >> 3, tb = blockIdx.x & 7;   // 8x8 blocks of 64x64
  __shared__ float woS[64][65];   // [kk][aa]
  __shared__ float wvS[64][65];   // [bb][kk]
  const int t = threadIdx.x;
  if (blockIdx.x == 0) {           // bpv = bv @ wo + bo
    for (int j = t; j < CCH; j += 256) {
      float a2 = bo[j];
      for (int k2 = 0; k2 < CCH; ++k2) a2 += bv[k2] * wo[(size_t)k2 * CCH + j];
      bpv[j] = a2;
    }
  }
  const int aa0 = (t & 15) * 4, bb0 = (t >> 4) * 4;
  float acc[4][4] = {};
  for (int kt = 0; kt < CCH; kt += 64) {
    for (int i = t; i < 4096; i += 256) {
      const int r = i >> 6, c = i & 63;
      woS[r][c] = wo[(size_t)(kt + r) * CCH + ta * 64 + c];
      wvS[r][c] = wv[(size_t)(tb * 64 + r) * CCH + kt + c];
    }
    __syncthreads();
    #pragma unroll 8
    for (int kk = 0; kk < 64; ++kk) {
      float wo4[4], wv4[4];
      #pragma unroll
      for (int i2 = 0; i2 < 4; ++i2) { wo4[i2] = woS[kk][aa0 + i2]; wv4[i2] = wvS[bb0 + i2][kk]; }
      #pragma unroll
      for (int a2 = 0; a2 < 4; ++a2)
        #pragma unroll
        for (int b2 = 0; b2 < 4; ++b2)
          acc[a2][b2] += wo4[a2] * wv4[b2];
    }
    __syncthreads();
  }
  #pragma unroll
  for (int a2 = 0; a2 < 4; ++a2)
    #pragma unroll
    for (int b2 = 0; b2 < 4; ++b2)
      wpT[(size_t)(ta * 64 + aa0 + a2) * CCH + tb * 64 + bb0 + b2] = (bf16)acc[a2][b2];
}

// ---------------- row-sum reduce: partials[rows][32] -> rinv = 1/sum --------
__global__ __launch_bounds__(256) void rowsum_inv(const float* __restrict__ partials,
                                                  float* __restrict__ rinv) {
  const int row = blockIdx.x * 256 + threadIdx.x;
  const float* p = partials + (size_t)row * 32;
  float s = 0.f;
  #pragma unroll
  for (int j = 0; j < 32; ++j) s += p[j];
  rinv[row] = 1.f / s;
}

// ---------------- 4-phase 256x128 bf16 MFMA GEMM (QK proj / V'^T) -----------
// As R16; epilogue stores fp8 at kperm(col).
// EPI: 0 = fp8 out of (val + bias), UNSCALED (QK proj; panel map)
//      4 = fp8 out (V'^T; old XCD swizzle map since nbm=2)
template <int EPI>
__global__ __launch_bounds__(512, 2) void gemm256(
    const bf16* __restrict__ A, int lda,
    const bf16* __restrict__ Bt, int ldb,
    unsigned char* __restrict__ C, int ldc,
    const float* __restrict__ bias,
    int M, int N, int K) {
  constexpr int BK = 64;
  constexpr int BNt = 128;
  constexpr int WN = 32;
  constexpr int NREP = 2;

  __shared__ bf16 Al[2][256 * BK];
  __shared__ bf16 Bl[2][BNt * BK];

  const int tid = threadIdx.x;
  const int lane = tid & 63;
  const int wave = tid >> 6;
  const int wm = wave >> 2, wn = wave & 3;
  const int fr = lane & 15, fq = lane >> 4;
  const int nbn = N / BNt;
  int bm, bn;
  if constexpr (EPI == 4) {
    const int nwg = gridDim.x;
    const int bx = (blockIdx.x & 7) * (nwg >> 3) + (blockIdx.x >> 3);
    bm = bx / nbn; bn = bx % nbn;
  } else {
    const int r = blockIdx.x & 7, q = blockIdx.x >> 3;
    const int pg = q / nbn;
    bm = r + 8 * pg;
    bn = q - pg * nbn;
  }

  const int srow = tid >> 3;
  const int scol = (((tid & 7) ^ (srow & 7)) * 8);
  const bf16* Ab = A + (size_t)(bm * 256 + srow) * lda + scol;
  const bf16* Bb = Bt + (size_t)(bn * BNt + srow) * ldb + scol;

  const int xk = fr & 7;
  const int c0 = ((0 + fq) ^ xk) * 8;
  const int c1 = ((4 + fq) ^ xk) * 8;
  const int aroff = (wm * 128 + fr) * BK;
  const int broff = (wn * WN + fr) * BK;

  f32x4 acc[8][NREP];
  #pragma unroll
  for (int m2 = 0; m2 < 8; ++m2)
    #pragma unroll
    for (int n2 = 0; n2 < NREP; ++n2)
      acc[m2][n2] = f32x4{0.f, 0.f, 0.f, 0.f};
  bf16x8 af[4][2];
  bf16x8 bfr[NREP][2];

#define STAGE_A(buf, h, kt)                                                     \
  { gload_lds16(Ab + (size_t)((h) * 128) * lda + (kt),                          \
                &Al[buf][(h) * 8192 + wave * 512]);                             \
    gload_lds16(Ab + (size_t)((h) * 128 + 64) * lda + (kt),                     \
                &Al[buf][(h) * 8192 + 4096 + wave * 512]); }
#define STAGE_B(buf, h, kt)                                                     \
  gload_lds16(Bb + (size_t)((h) * 64) * ldb + (kt),                             \
              &Bl[buf][(h) * 4096 + wave * 512]);
#define LOADA(buf, mh)                                                          \
  { _Pragma("unroll") for (int mi = 0; mi < 4; ++mi) {                          \
      af[mi][0] = *(const bf16x8*)&Al[buf][aroff + ((mh) * 64 + mi * 16) * BK + c0]; \
      af[mi][1] = *(const bf16x8*)&Al[buf][aroff + ((mh) * 64 + mi * 16) * BK + c1]; } }
#define LOADB(buf)                                                              \
  { _Pragma("unroll") for (int ni = 0; ni < NREP; ++ni) {                       \
      bfr[ni][0] = *(const bf16x8*)&Bl[buf][broff + (ni * 16) * BK + c0];       \
      bfr[ni][1] = *(const bf16x8*)&Bl[buf][broff + (ni * 16) * BK + c1]; } }
#define MMA(mh)                                                                 \
  { __builtin_amdgcn_s_setprio(1);                                              \
    _Pragma("unroll") for (int ks = 0; ks < 2; ++ks)                            \
      _Pragma("unroll") for (int mi = 0; mi < 4; ++mi)                          \
        _Pragma("unroll") for (int ni = 0; ni < NREP; ++ni)                     \
          acc[(mh) * 4 + mi][ni] = __builtin_amdgcn_mfma_f32_16x16x32_bf16(     \
              af[mi][ks], bfr[ni][ks], acc[(mh) * 4 + mi][ni], 0, 0, 0);        \
    __builtin_amdgcn_s_setprio(0); }
#define BARX() __builtin_amdgcn_s_barrier()
#define PIN() __builtin_amdgcn_sched_barrier(0)
#define LGKM0() { asm volatile("s_waitcnt lgkmcnt(0)" ::: "memory"); PIN(); }
#define VMW(n) asm volatile("s_waitcnt vmcnt(" #n ")" ::: "memory")

  STAGE_A(0, 0, 0); STAGE_A(0, 1, 0);
  STAGE_B(0, 0, 0); STAGE_B(0, 1, 0);
  STAGE_A(1, 0, BK); STAGE_B(1, 0, BK);
  VMW(3);
  BARX();

  const int niter = K >> 7;
  for (int j = 0; j < niter; ++j) {
    const int kt1 = j * 128 + 64;
    const int kt2 = kt1 + 64, kt3 = kt1 + 128;
    const bool last = (j == niter - 1);
    LOADA(0, 0); LOADB(0); STAGE_A(1, 1, kt1); STAGE_B(1, 1, kt1);
    PIN(); BARX(); LGKM0(); MMA(0); BARX();
    LOADA(0, 1); if (!last) { STAGE_A(0, 0, kt2); STAGE_B(0, 0, kt2); }
    PIN(); BARX(); LGKM0(); MMA(1);
    if (last) { VMW(0); } else VMW(3);
    BARX();
    LOADA(1, 0); LOADB(1); if (!last) { STAGE_A(0, 1, kt2); STAGE_B(0, 1, kt2); }
    PIN(); BARX(); LGKM0(); MMA(0); BARX();
    LOADA(1, 1); if (!last) { STAGE_A(1, 0, kt3); STAGE_B(1, 0, kt3); }
    PIN(); BARX(); LGKM0(); MMA(1);
    if (!last) VMW(3);
    BARX();
  }

  const int crow0 = bm * 256 + wm * 128 + fq * 4;
  const int ccol0 = bn * BNt + wn * WN + fr;
  #pragma unroll
  for (int mh = 0; mh < 2; ++mh)
    #pragma unroll
    for (int mi = 0; mi < 4; ++mi)
      #pragma unroll
      for (int nr = 0; nr < NREP; ++nr)
        #pragma unroll
        for (int jj = 0; jj < 4; ++jj) {
          const int row = crow0 + mh * 64 + mi * 16 + jj;
          const int col = ccol0 + nr * 16;
          const float val = acc[mh * 4 + mi][nr][jj];
          const size_t idx = (size_t)row * ldc + kperm(col);
          if constexpr (EPI == 0) {
            C[idx] = to_e4m3(val + bias[col]);
          } else {
            C[idx] = to_e4m3(val);
          }
        }
#undef STAGE_A
#undef STAGE_B
#undef LOADA
#undef LOADB
#undef MMA
#undef BARX
#undef PIN
#undef LGKM0
#undef VMW
}

// ---------------- scores fp8: S8 = exp(sscale * q @ k^T), b128 reads --------
// As R16 + __align__(16) LDS (true ds_read_b128) + launch_bounds(512,6)
// (3 blocks/CU; VGPR 60 <= 85 cap, LDS 48KB allows 3).
__global__ __launch_bounds__(512, 6) void scores_fp8(
    const unsigned char* __restrict__ qk,   // [B][4096][1024] kperm'd
    unsigned char* __restrict__ S8,         // [B][4096][4096] kperm'd out
    float* __restrict__ partials,           // [B*4096][32]
    float sscale) {
  __shared__ __align__(16) unsigned char Ql[256 * 128];   // 32 KB
  __shared__ __align__(16) unsigned char Kl[128 * 128];   // 16 KB
  const int bb = blockIdx.y;
  const unsigned char* Aq = qk + (size_t)bb * NTOK * 1024;
  const int tid = threadIdx.x, lane = tid & 63, wave = tid >> 6;
  const int wm = wave >> 2, wn = wave & 3;
  const int fr = lane & 15, fq = lane >> 4;
  // panel-coherent XCD mapping: nbm=16, nbn=32, grid.x=512
  const int r_ = blockIdx.x & 7, q_ = blockIdx.x >> 3;
  const int pg = q_ >> 5;
  const int bm = r_ + 8 * pg, bn = q_ & 31;

  const int sr = tid >> 3;                  // staging row 0..63
  const int ssl = ((tid & 7) ^ (sr & 7)) * 16;
  const unsigned char* Ab = Aq + (size_t)(bm * 256 + sr) * 1024 + ssl;        // q
  const unsigned char* Bb = Aq + (size_t)(bn * 128 + sr) * 1024 + 512 + ssl;  // k

  const int xk = fr & 7;
  const int sA0 = ((2 * fq + 0) ^ xk) * 16;   // k-tile 0 slot byte
  const int sA1 = ((2 * fq + 1) ^ xk) * 16;   // k-tile 1 slot byte

  f32x4 acc[8][2];
  #pragma unroll
  for (int m2 = 0; m2 < 8; ++m2)
    #pragma unroll
    for (int n2 = 0; n2 < 2; ++n2)
      acc[m2][n2] = f32x4{0.f, 0.f, 0.f, 0.f};

  for (int it = 0; it < 4; ++it) {          // 128 B of K per iteration
    const int kt = it * 128;
    #pragma unroll
    for (int i = 0; i < 4; ++i)
      gload_lds16(Ab + (size_t)(i * 64) * 1024 + kt, (char*)Ql + i * 8192 + tid * 16);
    #pragma unroll
    for (int i = 0; i < 2; ++i)
      gload_lds16(Bb + (size_t)(i * 64) * 1024 + kt, (char*)Kl + i * 8192 + tid * 16);
    asm volatile("s_waitcnt vmcnt(0)" ::: "memory");
    __syncthreads();
    #pragma unroll
    for (int t = 0; t < 2; ++t) {
      const int sl = (t == 0) ? sA0 : sA1;
      i64x2 bfv[2];
      #pragma unroll
      for (int ni = 0; ni < 2; ++ni)
        bfv[ni] = *(const i64x2*)&Kl[(wn * 32 + ni * 16 + fr) * 128 + sl];
      #pragma unroll
      for (int mh = 0; mh < 2; ++mh) {
        i64x2 afv[4];
        #pragma unroll
        for (int mi = 0; mi < 4; ++mi)
          afv[mi] = *(const i64x2*)&Ql[(wm * 128 + mh * 64 + mi * 16 + fr) * 128 + sl];
        __builtin_amdgcn_s_setprio(1);
        #pragma unroll
        for (int ks = 0; ks < 2; ++ks)
          #pragma unroll
          for (int mi = 0; mi < 4; ++mi)
            #pragma unroll
            for (int ni = 0; ni < 2; ++ni)
              acc[mh * 4 + mi][ni] = __builtin_amdgcn_mfma_f32_16x16x32_fp8_fp8(
                  afv[mi][ks], bfv[ni][ks], acc[mh * 4 + mi][ni], 0, 0, 0);
        __builtin_amdgcn_s_setprio(0);
      }
    }
    __syncthreads();
  }

  // epilogue: exp + fp8 store (kperm'd col) + row-sum partials (nbn=32)
  unsigned char* Cb = S8 + (size_t)bb * NTOK * NTOK;
  const int crow0 = bm * 256 + wm * 128 + fq * 4;
  const int ccol0 = bn * 128 + wn * 32 + fr;
  float* sums = (float*)&Ql[0];             // [256 rows][4 wn] f32 (4 KB)
  #pragma unroll
  for (int mh = 0; mh < 2; ++mh)
    #pragma unroll
    for (int mi = 0; mi < 4; ++mi)
      #pragma unroll
      for (int jj = 0; jj < 4; ++jj) {
        const int row = crow0 + mh * 64 + mi * 16 + jj;
        float rs = 0.f;
        #pragma unroll
        for (int ni = 0; ni < 2; ++ni) {
          const float e = __expf(fminf(acc[mh * 4 + mi][ni][jj] * sscale, 6.10f));
          rs += e;
          Cb[(size_t)row * NTOK + kperm(ccol0 + ni * 16)] = to_e4m3(e);
        }
        rs += __shfl_xor(rs, 1); rs += __shfl_xor(rs, 2);
        rs += __shfl_xor(rs, 4); rs += __shfl_xor(rs, 8);
        if (fr == 0)
          sums[(wm * 128 + mh * 64 + mi * 16 + fq * 4 + jj) * 4 + wn] = rs;
      }
  __syncthreads();
  if (tid < 256) {
    const float s4 = sums[tid * 4] + sums[tid * 4 + 1] +
                     sums[tid * 4 + 2] + sums[tid * 4 + 3];
    partials[((size_t)bb * NTOK + bm * 256 + tid) * 32 + bn] = s4;
  }
}

// ---------------- PV fp8: out = x + (S8 @ V8^T)*rinv + bpv, b128 reads ------
// As R16 + __align__(16) LDS + launch_bounds(512,6) (3 blocks/CU).
__global__ __launch_bounds__(512, 6) void pv_fp8(
    const unsigned char* __restrict__ S8,   // [gridDim.y][4096][4096] kperm'd
    const unsigned char* __restrict__ V8,   // [512][16384] kperm'd
    float* __restrict__ out, const float* __restrict__ bpv,
    const float* __restrict__ x, const float* __restrict__ rinv, int vofs) {
  __shared__ __align__(16) unsigned char Sl[128 * 128];   // 16 KB
  __shared__ __align__(16) unsigned char Vl[128 * 128];   // 16 KB
  const int bb = blockIdx.y;
  const unsigned char* A8 = S8 + (size_t)bb * NTOK * NTOK;
  const int tid = threadIdx.x, lane = tid & 63, wave = tid >> 6;
  const int wm = wave >> 2, wn = wave & 3;
  const int fr = lane & 15, fq = lane >> 4;
  // panel-coherent XCD mapping: nbm=32, nbn=4, grid.x=128
  const int r_ = blockIdx.x & 7, q_ = blockIdx.x >> 3;   // q_ 0..15
  const int pg = q_ >> 2;                                // 0..3
  const int bm = r_ + 8 * pg;                            // 0..31
  const int bn = q_ & 3;

  const int sr = tid >> 3;                  // staging row 0..63
  const int ssl = ((tid & 7) ^ (sr & 7)) * 16;
  const unsigned char* Ab = A8 + (size_t)(bm * 128 + sr) * NTOK + ssl;
  const unsigned char* Bb = V8 + (size_t)(bn * 128 + sr) * (NB * NTOK)
                            + vofs + bb * NTOK + ssl;

  const int xk = fr & 7;
  const int sA0 = ((2 * fq + 0) ^ xk) * 16;
  const int sA1 = ((2 * fq + 1) ^ xk) * 16;

  f32x4 acc[4][2];
  #pragma unroll
  for (int m2 = 0; m2 < 4; ++m2)
    #pragma unroll
    for (int n2 = 0; n2 < 2; ++n2)
      acc[m2][n2] = f32x4{0.f, 0.f, 0.f, 0.f};

  for (int it = 0; it < 32; ++it) {         // 128 B of K per iteration
    const int kt = it * 128;
    #pragma unroll
    for (int i = 0; i < 2; ++i)
      gload_lds16(Ab + (size_t)(i * 64) * NTOK + kt, (char*)Sl + i * 8192 + tid * 16);
    #pragma unroll
    for (int i = 0; i < 2; ++i)
      gload_lds16(Bb + (size_t)(i * 64) * (NB * NTOK) + kt, (char*)Vl + i * 8192 + tid * 16);
    asm volatile("s_waitcnt vmcnt(0)" ::: "memory");
    __syncthreads();
    #pragma unroll
    for (int t = 0; t < 2; ++t) {
      const int sl = (t == 0) ? sA0 : sA1;
      i64x2 bfv[2];
      #pragma unroll
      for (int ni = 0; ni < 2; ++ni)
        bfv[ni] = *(const i64x2*)&Vl[(wn * 32 + ni * 16 + fr) * 128 + sl];
      i64x2 afv[4];
      #pragma unroll
      for (int mi = 0; mi < 4; ++mi)
        afv[mi] = *(const i64x2*)&Sl[(wm * 64 + mi * 16 + fr) * 128 + sl];
      __builtin_amdgcn_s_setprio(1);
      #pragma unroll
      for (int ks = 0; ks < 2; ++ks)
        #pragma unroll
        for (int mi = 0; mi < 4; ++mi)
          #pragma unroll
          for (int ni = 0; ni < 2; ++ni)
            acc[mi][ni] = __builtin_amdgcn_mfma_f32_16x16x32_fp8_fp8(
                afv[mi][ks], bfv[ni][ks], acc[mi][ni], 0, 0, 0);
      __builtin_amdgcn_s_setprio(0);
    }
    __syncthreads();
  }

  // epilogue: out = acc*rinv + bpv + x (f32); output cols NOT permuted
  const int crow0 = bm * 128 + wm * 64 + fq * 4;
  const int ccol0 = bn * 128 + wn * 32 + fr;
  #pragma unroll
  for (int mi = 0; mi < 4; ++mi)
    #pragma unroll
    for (int jj = 0; jj < 4; ++jj) {
      const int row = crow0 + mi * 16 + jj;
      const float ri = rinv[(size_t)bb * NTOK + row];
      #pragma unroll
      for (int ni = 0; ni < 2; ++ni) {
        const int col = ccol0 + ni * 16;
        const size_t idx = ((size_t)bb * NTOK + row) * CCH + col;
        out[idx] = acc[mi][ni][jj] * ri + bpv[col] + x[idx];
      }
    }
}

// ---------------------------------------------------------------------------
extern "C" void kernel_launch(void* const* d_in, const int* in_sizes, int n_in,
                              void* d_out, int out_size, void* d_ws, size_t ws_size,
                              hipStream_t stream) {
  const float* x   = (const float*)d_in[0];
  const float* gsc = (const float*)d_in[1];
  const float* gbi = (const float*)d_in[2];
  const float* wq  = (const float*)d_in[3];
  const float* bq  = (const float*)d_in[4];
  const float* wk  = (const float*)d_in[5];
  const float* bk  = (const float*)d_in[6];
  const float* wv  = (const float*)d_in[7];
  const float* bv  = (const float*)d_in[8];
  const float* wo  = (const float*)d_in[9];
  const float* bo  = (const float*)d_in[10];
  float* out = (float*)d_out;
  char* ws = (char*)d_ws;

  const float sscale = 0.044194173824159216f;  // 1/sqrt(512)
  const bool batched = ws_size >= 96082944ULL;

  if (batched) {
    // S8[67.1M, aliases hf] | qk8[16.8M] | vt8[8.4M] | wT | small | spart | rinv
    unsigned char* S8  = (unsigned char*)(ws + 0);
    bf16*  hf    = (bf16*)(ws + 0);              // dead before S8 written
    unsigned char* qk8 = (unsigned char*)(ws + 67108864);
    unsigned char* vt8 = (unsigned char*)(ws + 83886080);
    bf16*  wT    = (bf16*)(ws + 92274688);       // wqT | wkT | W'T
    float* bcat  = (float*)(ws + 93847552);
    float* bpv   = (float*)(ws + 93851648);
    float* stats = (float*)(ws + 93853696);
    float* parts = (float*)(ws + 93854720);
    float* spart = (float*)(ws + 93920256);      // 16384 x 32 f32 = 2 MB
    float* rinv  = (float*)(ws + 96017408);      // 16384 f32

    gn_partial<<<dim3(64, NB), 256, 0, stream>>>((const float4*)x, parts);
    gn_reduce<<<1, 128, 0, stream>>>(parts, stats);
    gn_apply<<<8192, 256, 0, stream>>>((const float4*)x, stats, gsc, gbi, hf);
    wcast_t<<<dim3(64, 2), 256, 0, stream>>>(wq, wk, bq, bk, wT, bcat);
    prep_w<<<64, 256, 0, stream>>>(wv, wo, bv, bo, wT + 2 * CCH * CCH, bpv);

    // QK proj -> fp8 (unscaled, kperm'd): [16384,512] @ [1024,512]^T.
    gemm256<0><<<dim3(512, 1), 512, 0, stream>>>(
        hf, 512, wT, 512, qk8, 1024, bcat, 16384, 1024, 512);
    // V'^T fp8 (kperm'd): vt8[d][tok] = W'^T @ hf^T. 256 blocks.
    gemm256<4><<<dim3(256, 1), 512, 0, stream>>>(
        wT + 2 * CCH * CCH, 512, hf, 512, vt8, 16384, nullptr, 512, 16384, 512);
    // scores fp8: S8 = exp(sscale * q k^T) + row-sum partials. 512 x 4.
    scores_fp8<<<dim3(512, NB), 512, 0, stream>>>(qk8, S8, spart, sscale);
    rowsum_inv<<<64, 256, 0, stream>>>(spart, rinv);
    // PV fp8: out = x + (S8 @ V8^T)*rinv + bpv. 128 blocks x 4 batches.
    pv_fp8<<<dim3(128, NB), 512, 0, stream>>>(S8, vt8, out, bpv, x, rinv, 0);
  } else {
    // fallback: per-batch S8_1[16.8M, aliases hf] | qk8 | vt8 | wT | small
    unsigned char* S81 = (unsigned char*)(ws + 0);
    bf16*  hf    = (bf16*)(ws + 0);
    unsigned char* qk8 = (unsigned char*)(ws + 16777216);
    unsigned char* vt8 = (unsigned char*)(ws + 33554432);
    bf16*  wT    = (bf16*)(ws + 41943040);
    float* bcat  = (float*)(ws + 43515904);
    float* bpv   = (float*)(ws + 43520000);
    float* stats = (float*)(ws + 43522048);
    float* parts = (float*)(ws + 43523072);
    float* spart = (float*)(ws + 43588608);     // 4096 x 32 f32
    float* rinv  = (float*)(ws + 44112896);     // 4096 f32

    gn_partial<<<dim3(64, NB), 256, 0, stream>>>((const float4*)x, parts);
    gn_reduce<<<1, 128, 0, stream>>>(parts, stats);
    gn_apply<<<8192, 256, 0, stream>>>((const float4*)x, stats, gsc, gbi, hf);
    wcast_t<<<dim3(64, 2), 256, 0, stream>>>(wq, wk, bq, bk, wT, bcat);
    prep_w<<<64, 256, 0, stream>>>(wv, wo, bv, bo, wT + 2 * CCH * CCH, bpv);
    gemm256<0><<<dim3(512, 1), 512, 0, stream>>>(
        hf, 512, wT, 512, qk8, 1024, bcat, 16384, 1024, 512);
    gemm256<4><<<dim3(256, 1), 512, 0, stream>>>(
        wT + 2 * CCH * CCH, 512, hf, 512, vt8, 16384, nullptr, 512, 16384, 512);
    for (int b = 0; b < NB; ++b) {
      scores_fp8<<<dim3(512, 1), 512, 0, stream>>>(
          qk8 + (size_t)b * NTOK * 1024, S81, spart, sscale);
      rowsum_inv<<<16, 256, 0, stream>>>(spart, rinv);
      pv_fp8<<<dim3(128, 1), 512, 0, stream>>>(
          S81, vt8, out + (size_t)b * NTOK * CCH, bpv,
          x + (size_t)b * NTOK * CCH, rinv, b * NTOK);
    }
  }
}

// Round 18
// 249.644 us; speedup vs baseline: 2.2494x; 2.2494x over previous
//
#include <hip/hip_runtime.h>
#include <hip/hip_bf16.h>
#include <math.h>

// ---------------------------------------------------------------------------
// FlaxLTX2AudioAttnBlock: GN -> QKV proj -> softmax(QK^T/sqrt(C)) V -> proj -> +x
// B=4, N=4096 tokens/batch, C=512, G=32 groups.
// R18: revert R17's launch_bounds(512,6) -> (512,4). The 6-waves/EU hint
//      forced VGPR 60->40 and spilled the accumulators to scratch (WRITE_SIZE
//      1.27 GB/dispatch, scores 80->413us). Keep __align__(16) LDS (harmless).
//      Otherwise identical to R16 (best: 249.9us, absmax 0.03125).
// ---------------------------------------------------------------------------

typedef __bf16 bf16;
typedef float f32x4 __attribute__((ext_vector_type(4)));
typedef __bf16 bf16x8 __attribute__((ext_vector_type(8)));
typedef __bf16 bf16x4 __attribute__((ext_vector_type(4)));
typedef long long i64;
typedef __attribute__((ext_vector_type(2))) long long i64x2;

#define AS1 __attribute__((address_space(1)))
#define AS3 __attribute__((address_space(3)))

#define NB   4
#define NTOK 4096
#define CCH  512
#define NGRP 32

__device__ __forceinline__ void gload_lds16(const void* g, void* l) {
  __builtin_amdgcn_global_load_lds((AS1 void*)(g), (AS3 void*)(l), 16, 0, 0);
}

// f32 -> OCP e4m3 (RNE, saturating). HW cvt if available, manual otherwise.
__device__ __forceinline__ unsigned char to_e4m3(float f) {
#if __has_builtin(__builtin_amdgcn_cvt_pk_fp8_f32)
  return (unsigned char)(__builtin_amdgcn_cvt_pk_fp8_f32(f, 0.f, 0, false) & 0xff);
#else
  const unsigned u = __float_as_uint(f);
  const unsigned s = (u >> 24) & 0x80;
  const float a = fabsf(f);
  if (a >= 448.f) return (unsigned char)(s | 0x7E);
  if (a < 0.015625f) {
    const int m = (int)rintf(a * 512.f);
    return (unsigned char)(s | m);
  }
  int e = (int)((u >> 23) & 0xff) - 127;
  const float q = exp2f((float)(e - 3));
  int r = (int)rintf(a / q);
  if (r == 16) { e += 1; r = 8; }
  return (unsigned char)(s | ((e + 7) << 3) | (r - 8));
#endif
}

// k-byte permutation within each 128B block: granule g -> (g&3)*4 + (g>>2).
__device__ __forceinline__ int kperm(int col) {
  const int g = (col >> 3) & 15;
  const int gp = (g & 3) * 4 + (g >> 2);
  return (col & ~127) | (gp * 8) | (col & 7);
}

// ---------------- GroupNorm stage 1: partial sums ---------------------------
__global__ __launch_bounds__(256) void gn_partial(const float4* __restrict__ x4,
                                                  float* __restrict__ partials) {
  const int chunk = blockIdx.x, b = blockIdx.y;
  const int tid = threadIdx.x;
  const size_t base = ((size_t)b * NTOK + (size_t)chunk * 64) * 128;  // float4s
  float s = 0.f, ss = 0.f;
  #pragma unroll 4
  for (int it = 0; it < 32; ++it) {
    const float4 v = x4[base + it * 256 + tid];
    s  += v.x + v.y + v.z + v.w;
    ss += v.x * v.x + v.y * v.y + v.z * v.z + v.w * v.w;
  }
  __shared__ float ls[256], lss[256];
  ls[tid] = s; lss[tid] = ss;
  __syncthreads();
  if (tid < 32) {
    float ps = 0.f, pss = 0.f;
    #pragma unroll
    for (int j = 0; j < 4; ++j) {
      ps  += ls[tid * 4 + j] + ls[128 + tid * 4 + j];
      pss += lss[tid * 4 + j] + lss[128 + tid * 4 + j];
    }
    const size_t o = (((size_t)b * 64 + chunk) * 32 + tid) * 2;
    partials[o] = ps; partials[o + 1] = pss;
  }
}

// ---------------- GroupNorm stage 2: reduce 64 chunks -> stats --------------
__global__ __launch_bounds__(128) void gn_reduce(const float* __restrict__ partials,
                                                 float* __restrict__ stats) {
  const int tid = threadIdx.x;          // tid = b*32 + g
  const int b = tid >> 5, g = tid & 31;
  float s = 0.f, ss = 0.f;
  for (int c = 0; c < 64; ++c) {
    const size_t o = (((size_t)b * 64 + c) * 32 + g) * 2;
    s += partials[o]; ss += partials[o + 1];
  }
  const float inv = 1.f / (NTOK * 16.f);
  const float mean = s * inv;
  const float var = ss * inv - mean * mean;
  stats[tid * 2] = mean;
  stats[tid * 2 + 1] = rsqrtf(var + 1e-6f);
}

// ---------------- normalize + affine + cast to bf16 -------------------------
__global__ __launch_bounds__(256) void gn_apply(const float4* __restrict__ x4,
                                                const float* __restrict__ stats,
                                                const float* __restrict__ gsc,
                                                const float* __restrict__ gbi,
                                                bf16* __restrict__ hf) {
  const int i = blockIdx.x * 256 + threadIdx.x;   // over 2,097,152 float4s
  const float4 v = x4[i];
  const size_t e = (size_t)i * 4;
  const int c = (int)(e & (CCH - 1));
  const int b = (int)(e >> 21);
  const int g = c >> 4;
  const float mean = stats[(b * NGRP + g) * 2];
  const float rstd = stats[(b * NGRP + g) * 2 + 1];
  bf16x4 o;
  o[0] = (bf16)((v.x - mean) * rstd * gsc[c + 0] + gbi[c + 0]);
  o[1] = (bf16)((v.y - mean) * rstd * gsc[c + 1] + gbi[c + 1]);
  o[2] = (bf16)((v.z - mean) * rstd * gsc[c + 2] + gbi[c + 2]);
  o[3] = (bf16)((v.w - mean) * rstd * gsc[c + 3] + gbi[c + 3]);
  *reinterpret_cast<bf16x4*>(&hf[e]) = o;
}

// ---------------- weight transpose+cast (wq, wk) + bias concat --------------
__global__ __launch_bounds__(256) void wcast_t(const float* __restrict__ wq,
                                               const float* __restrict__ wk,
                                               const float* __restrict__ bq,
                                               const float* __restrict__ bk,
                                               bf16* __restrict__ dst,
                                               float* __restrict__ bcat) {
  const int w = blockIdx.y;                // 0 = wq, 1 = wk
  const float* src = (w == 0) ? wq : wk;
  bf16* out = dst + (size_t)w * CCH * CCH;
  const int t = blockIdx.x;                // 8x8 tiles of 64x64
  const int tr = t >> 3, tc = t & 7;
  if (t == 0) {
    const float* bsrc = (w == 0) ? bq : bk;
    for (int i = threadIdx.x; i < CCH; i += 256) bcat[w * CCH + i] = bsrc[i];
  }
  __shared__ float tile[64][65];
  for (int i = threadIdx.x; i < 4096; i += 256) {
    const int r = i >> 6, c = i & 63;
    tile[r][c] = src[(size_t)(tr * 64 + r) * CCH + tc * 64 + c];
  }
  __syncthreads();
  for (int i = threadIdx.x; i < 4096; i += 256) {
    const int r = i >> 6, c = i & 63;
    out[(size_t)(tc * 64 + r) * CCH + tr * 64 + c] = (bf16)tile[c][r];
  }
}

// ---------------- prep: W'^T = (wv@wo)^T bf16; block 0 also bpv -------------
__global__ __launch_bounds__(256) void prep_w(const float* __restrict__ wv,
                                              const float* __restrict__ wo,
                                              const float* __restrict__ bv,
                                              const float* __restrict__ bo,
                                              bf16* __restrict__ wpT,
                                              float* __restrict__ bpv) {
  const int ta = blockIdx.x >> 3, tb = blockIdx.x & 7;   // 8x8 blocks of 64x64
  __shared__ float woS[64][65];   // [kk][aa]
  __shared__ float wvS[64][65];   // [bb][kk]
  const int t = threadIdx.x;
  if (blockIdx.x == 0) {           // bpv = bv @ wo + bo
    for (int j = t; j < CCH; j += 256) {
      float a2 = bo[j];
      for (int k2 = 0; k2 < CCH; ++k2) a2 += bv[k2] * wo[(size_t)k2 * CCH + j];
      bpv[j] = a2;
    }
  }
  const int aa0 = (t & 15) * 4, bb0 = (t >> 4) * 4;
  float acc[4][4] = {};
  for (int kt = 0; kt < CCH; kt += 64) {
    for (int i = t; i < 4096; i += 256) {
      const int r = i >> 6, c = i & 63;
      woS[r][c] = wo[(size_t)(kt + r) * CCH + ta * 64 + c];
      wvS[r][c] = wv[(size_t)(tb * 64 + r) * CCH + kt + c];
    }
    __syncthreads();
    #pragma unroll 8
    for (int kk = 0; kk < 64; ++kk) {
      float wo4[4], wv4[4];
      #pragma unroll
      for (int i2 = 0; i2 < 4; ++i2) { wo4[i2] = woS[kk][aa0 + i2]; wv4[i2] = wvS[bb0 + i2][kk]; }
      #pragma unroll
      for (int a2 = 0; a2 < 4; ++a2)
        #pragma unroll
        for (int b2 = 0; b2 < 4; ++b2)
          acc[a2][b2] += wo4[a2] * wv4[b2];
    }
    __syncthreads();
  }
  #pragma unroll
  for (int a2 = 0; a2 < 4; ++a2)
    #pragma unroll
    for (int b2 = 0; b2 < 4; ++b2)
      wpT[(size_t)(ta * 64 + aa0 + a2) * CCH + tb * 64 + bb0 + b2] = (bf16)acc[a2][b2];
}

// ---------------- row-sum reduce: partials[rows][32] -> rinv = 1/sum --------
__global__ __launch_bounds__(256) void rowsum_inv(const float* __restrict__ partials,
                                                  float* __restrict__ rinv) {
  const int row = blockIdx.x * 256 + threadIdx.x;
  const float* p = partials + (size_t)row * 32;
  float s = 0.f;
  #pragma unroll
  for (int j = 0; j < 32; ++j) s += p[j];
  rinv[row] = 1.f / s;
}

// ---------------- 4-phase 256x128 bf16 MFMA GEMM (QK proj / V'^T) -----------
// As R16; epilogue stores fp8 at kperm(col).
// EPI: 0 = fp8 out of (val + bias), UNSCALED (QK proj; panel map)
//      4 = fp8 out (V'^T; old XCD swizzle map since nbm=2)
template <int EPI>
__global__ __launch_bounds__(512, 2) void gemm256(
    const bf16* __restrict__ A, int lda,
    const bf16* __restrict__ Bt, int ldb,
    unsigned char* __restrict__ C, int ldc,
    const float* __restrict__ bias,
    int M, int N, int K) {
  constexpr int BK = 64;
  constexpr int BNt = 128;
  constexpr int WN = 32;
  constexpr int NREP = 2;

  __shared__ bf16 Al[2][256 * BK];
  __shared__ bf16 Bl[2][BNt * BK];

  const int tid = threadIdx.x;
  const int lane = tid & 63;
  const int wave = tid >> 6;
  const int wm = wave >> 2, wn = wave & 3;
  const int fr = lane & 15, fq = lane >> 4;
  const int nbn = N / BNt;
  int bm, bn;
  if constexpr (EPI == 4) {
    const int nwg = gridDim.x;
    const int bx = (blockIdx.x & 7) * (nwg >> 3) + (blockIdx.x >> 3);
    bm = bx / nbn; bn = bx % nbn;
  } else {
    const int r = blockIdx.x & 7, q = blockIdx.x >> 3;
    const int pg = q / nbn;
    bm = r + 8 * pg;
    bn = q - pg * nbn;
  }

  const int srow = tid >> 3;
  const int scol = (((tid & 7) ^ (srow & 7)) * 8);
  const bf16* Ab = A + (size_t)(bm * 256 + srow) * lda + scol;
  const bf16* Bb = Bt + (size_t)(bn * BNt + srow) * ldb + scol;

  const int xk = fr & 7;
  const int c0 = ((0 + fq) ^ xk) * 8;
  const int c1 = ((4 + fq) ^ xk) * 8;
  const int aroff = (wm * 128 + fr) * BK;
  const int broff = (wn * WN + fr) * BK;

  f32x4 acc[8][NREP];
  #pragma unroll
  for (int m2 = 0; m2 < 8; ++m2)
    #pragma unroll
    for (int n2 = 0; n2 < NREP; ++n2)
      acc[m2][n2] = f32x4{0.f, 0.f, 0.f, 0.f};
  bf16x8 af[4][2];
  bf16x8 bfr[NREP][2];

#define STAGE_A(buf, h, kt)                                                     \
  { gload_lds16(Ab + (size_t)((h) * 128) * lda + (kt),                          \
                &Al[buf][(h) * 8192 + wave * 512]);                             \
    gload_lds16(Ab + (size_t)((h) * 128 + 64) * lda + (kt),                     \
                &Al[buf][(h) * 8192 + 4096 + wave * 512]); }
#define STAGE_B(buf, h, kt)                                                     \
  gload_lds16(Bb + (size_t)((h) * 64) * ldb + (kt),                             \
              &Bl[buf][(h) * 4096 + wave * 512]);
#define LOADA(buf, mh)                                                          \
  { _Pragma("unroll") for (int mi = 0; mi < 4; ++mi) {                          \
      af[mi][0] = *(const bf16x8*)&Al[buf][aroff + ((mh) * 64 + mi * 16) * BK + c0]; \
      af[mi][1] = *(const bf16x8*)&Al[buf][aroff + ((mh) * 64 + mi * 16) * BK + c1]; } }
#define LOADB(buf)                                                              \
  { _Pragma("unroll") for (int ni = 0; ni < NREP; ++ni) {                       \
      bfr[ni][0] = *(const bf16x8*)&Bl[buf][broff + (ni * 16) * BK + c0];       \
      bfr[ni][1] = *(const bf16x8*)&Bl[buf][broff + (ni * 16) * BK + c1]; } }
#define MMA(mh)                                                                 \
  { __builtin_amdgcn_s_setprio(1);                                              \
    _Pragma("unroll") for (int ks = 0; ks < 2; ++ks)                            \
      _Pragma("unroll") for (int mi = 0; mi < 4; ++mi)                          \
        _Pragma("unroll") for (int ni = 0; ni < NREP; ++ni)                     \
          acc[(mh) * 4 + mi][ni] = __builtin_amdgcn_mfma_f32_16x16x32_bf16(     \
              af[mi][ks], bfr[ni][ks], acc[(mh) * 4 + mi][ni], 0, 0, 0);        \
    __builtin_amdgcn_s_setprio(0); }
#define BARX() __builtin_amdgcn_s_barrier()
#define PIN() __builtin_amdgcn_sched_barrier(0)
#define LGKM0() { asm volatile("s_waitcnt lgkmcnt(0)" ::: "memory"); PIN(); }
#define VMW(n) asm volatile("s_waitcnt vmcnt(" #n ")" ::: "memory")

  STAGE_A(0, 0, 0); STAGE_A(0, 1, 0);
  STAGE_B(0, 0, 0); STAGE_B(0, 1, 0);
  STAGE_A(1, 0, BK); STAGE_B(1, 0, BK);
  VMW(3);
  BARX();

  const int niter = K >> 7;
  for (int j = 0; j < niter; ++j) {
    const int kt1 = j * 128 + 64;
    const int kt2 = kt1 + 64, kt3 = kt1 + 128;
    const bool last = (j == niter - 1);
    LOADA(0, 0); LOADB(0); STAGE_A(1, 1, kt1); STAGE_B(1, 1, kt1);
    PIN(); BARX(); LGKM0(); MMA(0); BARX();
    LOADA(0, 1); if (!last) { STAGE_A(0, 0, kt2); STAGE_B(0, 0, kt2); }
    PIN(); BARX(); LGKM0(); MMA(1);
    if (last) { VMW(0); } else VMW(3);
    BARX();
    LOADA(1, 0); LOADB(1); if (!last) { STAGE_A(0, 1, kt2); STAGE_B(0, 1, kt2); }
    PIN(); BARX(); LGKM0(); MMA(0); BARX();
    LOADA(1, 1); if (!last) { STAGE_A(1, 0, kt3); STAGE_B(1, 0, kt3); }
    PIN(); BARX(); LGKM0(); MMA(1);
    if (!last) VMW(3);
    BARX();
  }

  const int crow0 = bm * 256 + wm * 128 + fq * 4;
  const int ccol0 = bn * BNt + wn * WN + fr;
  #pragma unroll
  for (int mh = 0; mh < 2; ++mh)
    #pragma unroll
    for (int mi = 0; mi < 4; ++mi)
      #pragma unroll
      for (int nr = 0; nr < NREP; ++nr)
        #pragma unroll
        for (int jj = 0; jj < 4; ++jj) {
          const int row = crow0 + mh * 64 + mi * 16 + jj;
          const int col = ccol0 + nr * 16;
          const float val = acc[mh * 4 + mi][nr][jj];
          const size_t idx = (size_t)row * ldc + kperm(col);
          if constexpr (EPI == 0) {
            C[idx] = to_e4m3(val + bias[col]);
          } else {
            C[idx] = to_e4m3(val);
          }
        }
#undef STAGE_A
#undef STAGE_B
#undef LOADA
#undef LOADB
#undef MMA
#undef BARX
#undef PIN
#undef LGKM0
#undef VMW
}

// ---------------- scores fp8: S8 = exp(sscale * q @ k^T), b128 reads --------
// As R16 (launch_bounds(512,4) -- (512,6) spilled acc to scratch in R17).
__global__ __launch_bounds__(512, 4) void scores_fp8(
    const unsigned char* __restrict__ qk,   // [B][4096][1024] kperm'd
    unsigned char* __restrict__ S8,         // [B][4096][4096] kperm'd out
    float* __restrict__ partials,           // [B*4096][32]
    float sscale) {
  __shared__ __align__(16) unsigned char Ql[256 * 128];   // 32 KB
  __shared__ __align__(16) unsigned char Kl[128 * 128];   // 16 KB
  const int bb = blockIdx.y;
  const unsigned char* Aq = qk + (size_t)bb * NTOK * 1024;
  const int tid = threadIdx.x, lane = tid & 63, wave = tid >> 6;
  const int wm = wave >> 2, wn = wave & 3;
  const int fr = lane & 15, fq = lane >> 4;
  // panel-coherent XCD mapping: nbm=16, nbn=32, grid.x=512
  const int r_ = blockIdx.x & 7, q_ = blockIdx.x >> 3;
  const int pg = q_ >> 5;
  const int bm = r_ + 8 * pg, bn = q_ & 31;

  const int sr = tid >> 3;                  // staging row 0..63
  const int ssl = ((tid & 7) ^ (sr & 7)) * 16;
  const unsigned char* Ab = Aq + (size_t)(bm * 256 + sr) * 1024 + ssl;        // q
  const unsigned char* Bb = Aq + (size_t)(bn * 128 + sr) * 1024 + 512 + ssl;  // k

  const int xk = fr & 7;
  const int sA0 = ((2 * fq + 0) ^ xk) * 16;   // k-tile 0 slot byte
  const int sA1 = ((2 * fq + 1) ^ xk) * 16;   // k-tile 1 slot byte

  f32x4 acc[8][2];
  #pragma unroll
  for (int m2 = 0; m2 < 8; ++m2)
    #pragma unroll
    for (int n2 = 0; n2 < 2; ++n2)
      acc[m2][n2] = f32x4{0.f, 0.f, 0.f, 0.f};

  for (int it = 0; it < 4; ++it) {          // 128 B of K per iteration
    const int kt = it * 128;
    #pragma unroll
    for (int i = 0; i < 4; ++i)
      gload_lds16(Ab + (size_t)(i * 64) * 1024 + kt, (char*)Ql + i * 8192 + tid * 16);
    #pragma unroll
    for (int i = 0; i < 2; ++i)
      gload_lds16(Bb + (size_t)(i * 64) * 1024 + kt, (char*)Kl + i * 8192 + tid * 16);
    asm volatile("s_waitcnt vmcnt(0)" ::: "memory");
    __syncthreads();
    #pragma unroll
    for (int t = 0; t < 2; ++t) {
      const int sl = (t == 0) ? sA0 : sA1;
      i64x2 bfv[2];
      #pragma unroll
      for (int ni = 0; ni < 2; ++ni)
        bfv[ni] = *(const i64x2*)&Kl[(wn * 32 + ni * 16 + fr) * 128 + sl];
      #pragma unroll
      for (int mh = 0; mh < 2; ++mh) {
        i64x2 afv[4];
        #pragma unroll
        for (int mi = 0; mi < 4; ++mi)
          afv[mi] = *(const i64x2*)&Ql[(wm * 128 + mh * 64 + mi * 16 + fr) * 128 + sl];
        __builtin_amdgcn_s_setprio(1);
        #pragma unroll
        for (int ks = 0; ks < 2; ++ks)
          #pragma unroll
          for (int mi = 0; mi < 4; ++mi)
            #pragma unroll
            for (int ni = 0; ni < 2; ++ni)
              acc[mh * 4 + mi][ni] = __builtin_amdgcn_mfma_f32_16x16x32_fp8_fp8(
                  afv[mi][ks], bfv[ni][ks], acc[mh * 4 + mi][ni], 0, 0, 0);
        __builtin_amdgcn_s_setprio(0);
      }
    }
    __syncthreads();
  }

  // epilogue: exp + fp8 store (kperm'd col) + row-sum partials (nbn=32)
  unsigned char* Cb = S8 + (size_t)bb * NTOK * NTOK;
  const int crow0 = bm * 256 + wm * 128 + fq * 4;
  const int ccol0 = bn * 128 + wn * 32 + fr;
  float* sums = (float*)&Ql[0];             // [256 rows][4 wn] f32 (4 KB)
  #pragma unroll
  for (int mh = 0; mh < 2; ++mh)
    #pragma unroll
    for (int mi = 0; mi < 4; ++mi)
      #pragma unroll
      for (int jj = 0; jj < 4; ++jj) {
        const int row = crow0 + mh * 64 + mi * 16 + jj;
        float rs = 0.f;
        #pragma unroll
        for (int ni = 0; ni < 2; ++ni) {
          const float e = __expf(fminf(acc[mh * 4 + mi][ni][jj] * sscale, 6.10f));
          rs += e;
          Cb[(size_t)row * NTOK + kperm(ccol0 + ni * 16)] = to_e4m3(e);
        }
        rs += __shfl_xor(rs, 1); rs += __shfl_xor(rs, 2);
        rs += __shfl_xor(rs, 4); rs += __shfl_xor(rs, 8);
        if (fr == 0)
          sums[(wm * 128 + mh * 64 + mi * 16 + fq * 4 + jj) * 4 + wn] = rs;
      }
  __syncthreads();
  if (tid < 256) {
    const float s4 = sums[tid * 4] + sums[tid * 4 + 1] +
                     sums[tid * 4 + 2] + sums[tid * 4 + 3];
    partials[((size_t)bb * NTOK + bm * 256 + tid) * 32 + bn] = s4;
  }
}

// ---------------- PV fp8: out = x + (S8 @ V8^T)*rinv + bpv, b128 reads ------
// As R16 (launch_bounds(512,4)).
__global__ __launch_bounds__(512, 4) void pv_fp8(
    const unsigned char* __restrict__ S8,   // [gridDim.y][4096][4096] kperm'd
    const unsigned char* __restrict__ V8,   // [512][16384] kperm'd
    float* __restrict__ out, const float* __restrict__ bpv,
    const float* __restrict__ x, const float* __restrict__ rinv, int vofs) {
  __shared__ __align__(16) unsigned char Sl[128 * 128];   // 16 KB
  __shared__ __align__(16) unsigned char Vl[128 * 128];   // 16 KB
  const int bb = blockIdx.y;
  const unsigned char* A8 = S8 + (size_t)bb * NTOK * NTOK;
  const int tid = threadIdx.x, lane = tid & 63, wave = tid >> 6;
  const int wm = wave >> 2, wn = wave & 3;
  const int fr = lane & 15, fq = lane >> 4;
  // panel-coherent XCD mapping: nbm=32, nbn=4, grid.x=128
  const int r_ = blockIdx.x & 7, q_ = blockIdx.x >> 3;   // q_ 0..15
  const int pg = q_ >> 2;                                // 0..3
  const int bm = r_ + 8 * pg;                            // 0..31
  const int bn = q_ & 3;

  const int sr = tid >> 3;                  // staging row 0..63
  const int ssl = ((tid & 7) ^ (sr & 7)) * 16;
  const unsigned char* Ab = A8 + (size_t)(bm * 128 + sr) * NTOK + ssl;
  const unsigned char* Bb = V8 + (size_t)(bn * 128 + sr) * (NB * NTOK)
                            + vofs + bb * NTOK + ssl;

  const int xk = fr & 7;
  const int sA0 = ((2 * fq + 0) ^ xk) * 16;
  const int sA1 = ((2 * fq + 1) ^ xk) * 16;

  f32x4 acc[4][2];
  #pragma unroll
  for (int m2 = 0; m2 < 4; ++m2)
    #pragma unroll
    for (int n2 = 0; n2 < 2; ++n2)
      acc[m2][n2] = f32x4{0.f, 0.f, 0.f, 0.f};

  for (int it = 0; it < 32; ++it) {         // 128 B of K per iteration
    const int kt = it * 128;
    #pragma unroll
    for (int i = 0; i < 2; ++i)
      gload_lds16(Ab + (size_t)(i * 64) * NTOK + kt, (char*)Sl + i * 8192 + tid * 16);
    #pragma unroll
    for (int i = 0; i < 2; ++i)
      gload_lds16(Bb + (size_t)(i * 64) * (NB * NTOK) + kt, (char*)Vl + i * 8192 + tid * 16);
    asm volatile("s_waitcnt vmcnt(0)" ::: "memory");
    __syncthreads();
    #pragma unroll
    for (int t = 0; t < 2; ++t) {
      const int sl = (t == 0) ? sA0 : sA1;
      i64x2 bfv[2];
      #pragma unroll
      for (int ni = 0; ni < 2; ++ni)
        bfv[ni] = *(const i64x2*)&Vl[(wn * 32 + ni * 16 + fr) * 128 + sl];
      i64x2 afv[4];
      #pragma unroll
      for (int mi = 0; mi < 4; ++mi)
        afv[mi] = *(const i64x2*)&Sl[(wm * 64 + mi * 16 + fr) * 128 + sl];
      __builtin_amdgcn_s_setprio(1);
      #pragma unroll
      for (int ks = 0; ks < 2; ++ks)
        #pragma unroll
        for (int mi = 0; mi < 4; ++mi)
          #pragma unroll
          for (int ni = 0; ni < 2; ++ni)
            acc[mi][ni] = __builtin_amdgcn_mfma_f32_16x16x32_fp8_fp8(
                afv[mi][ks], bfv[ni][ks], acc[mi][ni], 0, 0, 0);
      __builtin_amdgcn_s_setprio(0);
    }
    __syncthreads();
  }

  // epilogue: out = acc*rinv + bpv + x (f32); output cols NOT permuted
  const int crow0 = bm * 128 + wm * 64 + fq * 4;
  const int ccol0 = bn * 128 + wn * 32 + fr;
  #pragma unroll
  for (int mi = 0; mi < 4; ++mi)
    #pragma unroll
    for (int jj = 0; jj < 4; ++jj) {
      const int row = crow0 + mi * 16 + jj;
      const float ri = rinv[(size_t)bb * NTOK + row];
      #pragma unroll
      for (int ni = 0; ni < 2; ++ni) {
        const int col = ccol0 + ni * 16;
        const size_t idx = ((size_t)bb * NTOK + row) * CCH + col;
        out[idx] = acc[mi][ni][jj] * ri + bpv[col] + x[idx];
      }
    }
}

// ---------------------------------------------------------------------------
extern "C" void kernel_launch(void* const* d_in, const int* in_sizes, int n_in,
                              void* d_out, int out_size, void* d_ws, size_t ws_size,
                              hipStream_t stream) {
  const float* x   = (const float*)d_in[0];
  const float* gsc = (const float*)d_in[1];
  const float* gbi = (const float*)d_in[2];
  const float* wq  = (const float*)d_in[3];
  const float* bq  = (const float*)d_in[4];
  const float* wk  = (const float*)d_in[5];
  const float* bk  = (const float*)d_in[6];
  const float* wv  = (const float*)d_in[7];
  const float* bv  = (const float*)d_in[8];
  const float* wo  = (const float*)d_in[9];
  const float* bo  = (const float*)d_in[10];
  float* out = (float*)d_out;
  char* ws = (char*)d_ws;

  const float sscale = 0.044194173824159216f;  // 1/sqrt(512)
  const bool batched = ws_size >= 96082944ULL;

  if (batched) {
    // S8[67.1M, aliases hf] | qk8[16.8M] | vt8[8.4M] | wT | small | spart | rinv
    unsigned char* S8  = (unsigned char*)(ws + 0);
    bf16*  hf    = (bf16*)(ws + 0);              // dead before S8 written
    unsigned char* qk8 = (unsigned char*)(ws + 67108864);
    unsigned char* vt8 = (unsigned char*)(ws + 83886080);
    bf16*  wT    = (bf16*)(ws + 92274688);       // wqT | wkT | W'T
    float* bcat  = (float*)(ws + 93847552);
    float* bpv   = (float*)(ws + 93851648);
    float* stats = (float*)(ws + 93853696);
    float* parts = (float*)(ws + 93854720);
    float* spart = (float*)(ws + 93920256);      // 16384 x 32 f32 = 2 MB
    float* rinv  = (float*)(ws + 96017408);      // 16384 f32

    gn_partial<<<dim3(64, NB), 256, 0, stream>>>((const float4*)x, parts);
    gn_reduce<<<1, 128, 0, stream>>>(parts, stats);
    gn_apply<<<8192, 256, 0, stream>>>((const float4*)x, stats, gsc, gbi, hf);
    wcast_t<<<dim3(64, 2), 256, 0, stream>>>(wq, wk, bq, bk, wT, bcat);
    prep_w<<<64, 256, 0, stream>>>(wv, wo, bv, bo, wT + 2 * CCH * CCH, bpv);

    // QK proj -> fp8 (unscaled, kperm'd): [16384,512] @ [1024,512]^T.
    gemm256<0><<<dim3(512, 1), 512, 0, stream>>>(
        hf, 512, wT, 512, qk8, 1024, bcat, 16384, 1024, 512);
    // V'^T fp8 (kperm'd): vt8[d][tok] = W'^T @ hf^T. 256 blocks.
    gemm256<4><<<dim3(256, 1), 512, 0, stream>>>(
        wT + 2 * CCH * CCH, 512, hf, 512, vt8, 16384, nullptr, 512, 16384, 512);
    // scores fp8: S8 = exp(sscale * q k^T) + row-sum partials. 512 x 4.
    scores_fp8<<<dim3(512, NB), 512, 0, stream>>>(qk8, S8, spart, sscale);
    rowsum_inv<<<64, 256, 0, stream>>>(spart, rinv);
    // PV fp8: out = x + (S8 @ V8^T)*rinv + bpv. 128 blocks x 4 batches.
    pv_fp8<<<dim3(128, NB), 512, 0, stream>>>(S8, vt8, out, bpv, x, rinv, 0);
  } else {
    // fallback: per-batch S8_1[16.8M, aliases hf] | qk8 | vt8 | wT | small
    unsigned char* S81 = (unsigned char*)(ws + 0);
    bf16*  hf    = (bf16*)(ws + 0);
    unsigned char* qk8 = (unsigned char*)(ws + 16777216);
    unsigned char* vt8 = (unsigned char*)(ws + 33554432);
    bf16*  wT    = (bf16*)(ws + 41943040);
    float* bcat  = (float*)(ws + 43515904);
    float* bpv   = (float*)(ws + 43520000);
    float* stats = (float*)(ws + 43522048);
    float* parts = (float*)(ws + 43523072);
    float* spart = (float*)(ws + 43588608);     // 4096 x 32 f32
    float* rinv  = (float*)(ws + 44112896);     // 4096 f32

    gn_partial<<<dim3(64, NB), 256, 0, stream>>>((const float4*)x, parts);
    gn_reduce<<<1, 128, 0, stream>>>(parts, stats);
    gn_apply<<<8192, 256, 0, stream>>>((const float4*)x, stats, gsc, gbi, hf);
    wcast_t<<<dim3(64, 2), 256, 0, stream>>>(wq, wk, bq, bk, wT, bcat);
    prep_w<<<64, 256, 0, stream>>>(wv, wo, bv, bo, wT + 2 * CCH * CCH, bpv);
    gemm256<0><<<dim3(512, 1), 512, 0, stream>>>(
        hf, 512, wT, 512, qk8, 1024, bcat, 16384, 1024, 512);
    gemm256<4><<<dim3(256, 1), 512, 0, stream>>>(
        wT + 2 * CCH * CCH, 512, hf, 512, vt8, 16384, nullptr, 512, 16384, 512);
    for (int b = 0; b < NB; ++b) {
      scores_fp8<<<dim3(512, 1), 512, 0, stream>>>(
          qk8 + (size_t)b * NTOK * 1024, S81, spart, sscale);
      rowsum_inv<<<16, 256, 0, stream>>>(spart, rinv);
      pv_fp8<<<dim3(128, 1), 512, 0, stream>>>(
          S81, vt8, out + (size_t)b * NTOK * CCH, bpv,
          x + (size_t)b * NTOK * CCH, rinv, b * NTOK);
    }
  }
}